// Round 7
// baseline (353.373 us; speedup 1.0000x reference)
//
#include <hip/hip_runtime.h>
#include <hip/hip_bf16.h>

typedef __attribute__((ext_vector_type(8))) short short8;
typedef __attribute__((ext_vector_type(4))) float f32x4;

#define HSZ 128
#define BM  64
#define NT  512

__device__ __forceinline__ unsigned short f2bf(float f) {
    union { float f; unsigned int u; } c; c.f = f;
    return (unsigned short)((c.u + 0x7FFFu + ((c.u >> 16) & 1u)) >> 16);
}

// Pack W (bf16) as Wp[col][k] (k contiguous, 16B-aligned fragments).
// W[k][g*128+i] = ih[g*128+k][i] (k<128) else hh[g*128+(k-128)][i].
__global__ void prep_kernel(const float* __restrict__ ih, const float* __restrict__ hh,
                            const float* __restrict__ ib, const float* __restrict__ hb,
                            unsigned short* __restrict__ Wp, float* __restrict__ bias) {
    int tid = blockIdx.x * blockDim.x + threadIdx.x;   // 0..16383
    int col = tid >> 5;                                // 0..511
    int kg  = tid & 31;                                // 0..31
    int g = col >> 7, i = col & 127;
    short8 pk;
    #pragma unroll
    for (int j = 0; j < 8; ++j) {
        int k = kg * 8 + j;
        float v = (k < HSZ) ? ih[(g * HSZ + k) * HSZ + i]
                            : hh[(g * HSZ + (k - HSZ)) * HSZ + i];
        pk[j] = (short)f2bf(v);
    }
    *reinterpret_cast<short8*>(Wp + col * 256 + kg * 8) = pk;
    if (kg == 0) bias[col] = ib[col] + hb[col];
}

union SMem {
    unsigned short A[BM * 264];   // 33792 B bf16 activations (dead after MFMA)
    float T[8][2048];             // per-wave 8 KB: 2 slots x 1024 f32 (16x64 tile)
};

__global__ __launch_bounds__(NT, 4)   // 2 blocks/CU
void lstm_kernel(const float* __restrict__ x, const float* __restrict__ h0,
                 const float* __restrict__ c0,
                 const unsigned short* __restrict__ Wp,
                 const float* __restrict__ biasp,
                 float* __restrict__ out, long BH) {
    constexpr int PITCH = 264;
    __shared__ SMem sm;

    const int t = threadIdx.x;
    const long rowBase = (long)blockIdx.x * BM;

    // ---- stage A = [x | h0] (64 rows x 256 k) as bf16 into LDS ----
    {
        const float4* x4 = reinterpret_cast<const float4*>(x + rowBase * HSZ);
        const float4* h4 = reinterpret_cast<const float4*>(h0 + rowBase * HSZ);
        #pragma unroll
        for (int j = 0; j < 4; ++j) {
            int fi = t + j * NT;               // 0..2047
            int row = fi >> 5;
            int c4  = fi & 31;
            float4 vx = x4[fi];
            float4 vh = h4[fi];
            ushort4 px; px.x = f2bf(vx.x); px.y = f2bf(vx.y); px.z = f2bf(vx.z); px.w = f2bf(vx.w);
            ushort4 ph; ph.x = f2bf(vh.x); ph.y = f2bf(vh.y); ph.z = f2bf(vh.z); ph.w = f2bf(vh.w);
            *reinterpret_cast<ushort4*>(&sm.A[row * PITCH + c4 * 4]) = px;
            *reinterpret_cast<ushort4*>(&sm.A[row * PITCH + HSZ + c4 * 4]) = ph;
        }
    }
    __syncthreads();

    const int lane = t & 63;
    const int wid  = t >> 6;
    const int wm = wid & 3;            // row quarter (16 rows)
    const int wn = wid >> 2;           // col half (64 of 128 intra-gate cols)
    const int lr = lane & 15;
    const int lk = lane >> 4;          // k-group (8 bf16)

    const char* Ab = reinterpret_cast<const char*>(sm.A)
                   + (wm * 16 + lr) * (PITCH * 2) + lk * 16;
    const char* Wb = reinterpret_cast<const char*>(Wp)
                   + (wn * 64 + lr) * 512 + lk * 16;

    f32x4 acc[4][4] = {};   // [ni][gate]

    #pragma unroll
    for (int ks = 0; ks < 8; ++ks) {
        short8 a0 = *reinterpret_cast<const short8*>(Ab + ks * 64);
        #pragma unroll
        for (int g = 0; g < 4; ++g) {
            #pragma unroll
            for (int ni = 0; ni < 4; ++ni) {
                short8 w = *reinterpret_cast<const short8*>(
                    Wb + (g * 128 + ni * 16) * 512 + ks * 64);
                // Swapped operands: lane's 4 acc regs = 4 consecutive gate cols
                acc[ni][g] = __builtin_amdgcn_mfma_f32_16x16x32_bf16(w, a0, acc[ni][g], 0, 0, 0);
            }
        }
    }

    // ---- c0 load (fragment layout) ----
    f32x4 c0v[4];
    #pragma unroll
    for (int ni = 0; ni < 4; ++ni) {
        long pos = (rowBase + wm * 16 + lr) * HSZ + wn * 64 + ni * 16 + lk * 4;
        c0v[ni] = *reinterpret_cast<const f32x4*>(c0 + pos);
    }

    // ---- fold bias into acc ----
    #pragma unroll
    for (int ni = 0; ni < 4; ++ni)
        #pragma unroll
        for (int g = 0; g < 4; ++g) {
            f32x4 bg = *reinterpret_cast<const f32x4*>(
                biasp + g * HSZ + wn * 64 + ni * 16 + lk * 4);
            acc[ni][g] += bg;
        }

    __syncthreads();   // A tile dead; LDS becomes per-wave transpose slots.

    float* wt = sm.T[wid];             // 2 slots x 1024 f32 (16 rows x 64 cols)
    const long rbase = (rowBase + wm * 16) * (long)HSZ + wn * 64;
    const int rr0 = lane >> 4;         // read-back: row within 4-row group
    const int gg0 = lane & 15;         // read-back: granule (16B) within 256B row-chunk

    // ---- c_1 -> slot0, h_1 -> slot1 ----
    #pragma unroll
    for (int ni = 0; ni < 4; ++ni) {
        int g4  = ni * 4 + lk;                       // granule col 0..15
        int idx = lr * 64 + ((g4 ^ lr) & 15) * 4;
        f32x4 c1v, h1v;
        #pragma unroll
        for (int r = 0; r < 4; ++r) {
            float iv = acc[ni][0][r];
            float fv = acc[ni][1][r];
            float gv = acc[ni][2][r];
            float ov = acc[ni][3][r];
            float si = 1.f / (1.f + __expf(-iv));
            float sf = 1.f / (1.f + __expf(-fv));
            float tg = 1.f - 2.f / (__expf(2.f * gv) + 1.f);
            float so = 1.f / (1.f + __expf(-ov));
            float c1 = c0v[ni][r] * sf + si * tg;
            float th = 1.f - 2.f / (__expf(2.f * c1) + 1.f);
            c1v[r] = c1;
            h1v[r] = so + th;
        }
        *reinterpret_cast<f32x4*>(&wt[idx])        = c1v;
        *reinterpret_cast<f32x4*>(&wt[1024 + idx]) = h1v;
    }
    __builtin_amdgcn_wave_barrier();

    // ---- flush c_1, h_1: 4 rows x 256B contiguous per instruction ----
    #pragma unroll
    for (int p = 0; p < 4; ++p) {
        int rr  = p * 4 + rr0;
        int idx = rr * 64 + ((gg0 ^ rr) & 15) * 4;
        f32x4 vc = *reinterpret_cast<const f32x4*>(&wt[idx]);
        f32x4 vh = *reinterpret_cast<const f32x4*>(&wt[1024 + idx]);
        long rpos = rbase + (long)rr * HSZ + gg0 * 4;
        *reinterpret_cast<f32x4*>(out + BH + rpos) = vc;
        *reinterpret_cast<f32x4*>(out + rpos)      = vh;
    }
    __builtin_amdgcn_wave_barrier();

    // ---- raw gates I, F, G, O via ping-pong slots ----
    #pragma unroll
    for (int g = 0; g < 4; ++g) {
        float* slot = wt + (g & 1) * 1024;
        #pragma unroll
        for (int ni = 0; ni < 4; ++ni) {
            int g4  = ni * 4 + lk;
            int idx = lr * 64 + ((g4 ^ lr) & 15) * 4;
            *reinterpret_cast<f32x4*>(&slot[idx]) = acc[ni][g];
        }
        __builtin_amdgcn_wave_barrier();
        #pragma unroll
        for (int p = 0; p < 4; ++p) {
            int rr  = p * 4 + rr0;
            int idx = rr * 64 + ((gg0 ^ rr) & 15) * 4;
            f32x4 v = *reinterpret_cast<const f32x4*>(&slot[idx]);
            long rpos = rbase + (long)rr * HSZ + gg0 * 4;
            *reinterpret_cast<f32x4*>(out + (long)(2 + g) * BH + rpos) = v;
        }
        __builtin_amdgcn_wave_barrier();
    }
}

extern "C" void kernel_launch(void* const* d_in, const int* in_sizes, int n_in,
                              void* d_out, int out_size, void* d_ws, size_t ws_size,
                              hipStream_t stream) {
    const float* x  = (const float*)d_in[0];
    const float* h0 = (const float*)d_in[1];
    const float* c0 = (const float*)d_in[2];
    const float* ih = (const float*)d_in[3];
    const float* hh = (const float*)d_in[4];
    const float* ib = (const float*)d_in[5];
    const float* hb = (const float*)d_in[6];
    float* out = (float*)d_out;

    unsigned short* Wp = (unsigned short*)d_ws;            // 512*256 bf16 = 256 KB
    float* bias = (float*)((char*)d_ws + 512 * 256 * 2);   // 512 f32

    long BH = in_sizes[2];      // B * H
    long B  = BH / HSZ;

    prep_kernel<<<64, 256, 0, stream>>>(ih, hh, ib, hb, Wp, bias);
    lstm_kernel<<<(int)(B / BM), NT, 0, stream>>>(x, h0, c0, Wp, bias, out, BH);
}

// Round 8
// 314.695 us; speedup vs baseline: 1.1229x; 1.1229x over previous
//
#include <hip/hip_runtime.h>
#include <hip/hip_bf16.h>

typedef __attribute__((ext_vector_type(8))) short short8;
typedef __attribute__((ext_vector_type(4))) float f32x4;

#define HSZ 128
#define BM  16
#define NT  256

__device__ __forceinline__ unsigned short f2bf(float f) {
    union { float f; unsigned int u; } c; c.f = f;
    return (unsigned short)((c.u + 0x7FFFu + ((c.u >> 16) & 1u)) >> 16);
}

// Pack W (bf16) as Wp[col][k] (k contiguous, 16B-aligned fragments).
// W[k][g*128+i] = ih[g*128+k][i] (k<128) else hh[g*128+(k-128)][i].
__global__ void prep_kernel(const float* __restrict__ ih, const float* __restrict__ hh,
                            const float* __restrict__ ib, const float* __restrict__ hb,
                            unsigned short* __restrict__ Wp, float* __restrict__ bias) {
    int tid = blockIdx.x * blockDim.x + threadIdx.x;   // 0..16383
    int col = tid >> 5;                                // 0..511
    int kg  = tid & 31;                                // 0..31
    int g = col >> 7, i = col & 127;
    short8 pk;
    #pragma unroll
    for (int j = 0; j < 8; ++j) {
        int k = kg * 8 + j;
        float v = (k < HSZ) ? ih[(g * HSZ + k) * HSZ + i]
                            : hh[(g * HSZ + (k - HSZ)) * HSZ + i];
        pk[j] = (short)f2bf(v);
    }
    *reinterpret_cast<short8*>(Wp + col * 256 + kg * 8) = pk;
    if (kg == 0) bias[col] = ib[col] + hb[col];
}

union SMem {
    unsigned short A[BM * 264];   // 8448 B bf16 activations (dead after MFMA)
    float S[4][512];              // per-wave 2 KB slot: 16 rows x 32 cols f32
};

__global__ __launch_bounds__(NT, 4)   // 4 blocks/CU, caps VGPR+AGPR at 128
void lstm_kernel(const float* __restrict__ x, const float* __restrict__ h0,
                 const float* __restrict__ c0,
                 const unsigned short* __restrict__ Wp,
                 const float* __restrict__ biasp,
                 float* __restrict__ out, long BH) {
    constexpr int PITCH = 264;
    __shared__ SMem sm;

    const int t = threadIdx.x;
    const long rowBase = (long)blockIdx.x * BM;

    // ---- stage A = [x | h0] (16 rows x 256 k) as bf16 into LDS ----
    {
        const float4* x4 = reinterpret_cast<const float4*>(x + rowBase * HSZ);
        const float4* h4 = reinterpret_cast<const float4*>(h0 + rowBase * HSZ);
        #pragma unroll
        for (int j = 0; j < 2; ++j) {
            int fi = t + j * NT;               // 0..511
            int row = fi >> 5;
            int c4  = fi & 31;
            float4 vx = x4[fi];
            float4 vh = h4[fi];
            ushort4 px; px.x = f2bf(vx.x); px.y = f2bf(vx.y); px.z = f2bf(vx.z); px.w = f2bf(vx.w);
            ushort4 ph; ph.x = f2bf(vh.x); ph.y = f2bf(vh.y); ph.z = f2bf(vh.z); ph.w = f2bf(vh.w);
            *reinterpret_cast<ushort4*>(&sm.A[row * PITCH + c4 * 4]) = px;
            *reinterpret_cast<ushort4*>(&sm.A[row * PITCH + HSZ + c4 * 4]) = ph;
        }
    }
    __syncthreads();

    const int lane = t & 63;
    const int wid  = t >> 6;           // 0..3 = intra-gate col quarter (32 cols)
    const int wn = wid;
    const int lr = lane & 15;
    const int lk = lane >> 4;          // k-group (8 bf16)

    const char* Ab = reinterpret_cast<const char*>(sm.A)
                   + lr * (PITCH * 2) + lk * 16;
    const char* Wb = reinterpret_cast<const char*>(Wp)
                   + (wn * 32 + lr) * 512 + lk * 16;

    f32x4 acc[2][4] = {};   // [ni][gate], 32 AGPR

    #pragma unroll
    for (int ks = 0; ks < 8; ++ks) {
        short8 a0 = *reinterpret_cast<const short8*>(Ab + ks * 64);
        #pragma unroll
        for (int g = 0; g < 4; ++g) {
            #pragma unroll
            for (int ni = 0; ni < 2; ++ni) {
                short8 w = *reinterpret_cast<const short8*>(
                    Wb + (g * 128 + ni * 16) * 512 + ks * 64);
                // Swapped operands: lane's 4 acc regs = 4 consecutive gate cols
                acc[ni][g] = __builtin_amdgcn_mfma_f32_16x16x32_bf16(w, a0, acc[ni][g], 0, 0, 0);
            }
        }
    }

    // ---- c0 fragment loads ----
    f32x4 c0v[2];
    #pragma unroll
    for (int ni = 0; ni < 2; ++ni) {
        long pos = (rowBase + lr) * HSZ + wn * 32 + ni * 16 + lk * 4;
        c0v[ni] = *reinterpret_cast<const f32x4*>(c0 + pos);
    }

    // ---- fold bias into acc ----
    #pragma unroll
    for (int ni = 0; ni < 2; ++ni)
        #pragma unroll
        for (int g = 0; g < 4; ++g) {
            f32x4 bg = *reinterpret_cast<const f32x4*>(
                biasp + g * HSZ + wn * 32 + ni * 16 + lk * 4);
            acc[ni][g] += bg;
        }

    __syncthreads();   // A tile dead; LDS becomes per-wave slots (epilogue wave-local)

    float* slot = sm.S[wid];
    const int rr0 = lane >> 3;         // readback row within 8-row group
    const int gg0 = lane & 7;          // readback granule within 128B row-chunk
    const long cb = (long)(wn * 32 + gg0 * 4);

    // 8-deep rotated store buffers: forces 8 stores in flight per wave
    f32x4 b0, b1, b2, b3, b4, b5, b6, b7;

    #define WSLOT(V, NI) do { \
        int g4_ = (NI) * 4 + lk; \
        slot[lr * 32 + ((g4_ ^ (lr & 7)) * 4)] = 0, \
        *reinterpret_cast<f32x4*>(&slot[lr * 32 + ((g4_ ^ (lr & 7)) * 4)]) = (V); \
    } while (0)

    #define FLUSH(OBASE, BA, BB) do { \
        int ra_ = rr0, rb_ = 8 + rr0; \
        BA = *reinterpret_cast<const f32x4*>(&slot[ra_ * 32 + ((gg0 ^ (ra_ & 7)) * 4)]); \
        BB = *reinterpret_cast<const f32x4*>(&slot[rb_ * 32 + ((gg0 ^ (rb_ & 7)) * 4)]); \
        *reinterpret_cast<f32x4*>(out + (OBASE) + (rowBase + ra_) * HSZ + cb) = BA; \
        *reinterpret_cast<f32x4*>(out + (OBASE) + (rowBase + rb_) * HSZ + cb) = BB; \
    } while (0)

    // ---- plane 0: c_1 (compute c1 & h1 together, h1 kept in regs) ----
    f32x4 h1v[2];
    #pragma unroll
    for (int ni = 0; ni < 2; ++ni) {
        f32x4 c1v;
        #pragma unroll
        for (int r = 0; r < 4; ++r) {
            float iv = acc[ni][0][r];
            float fv = acc[ni][1][r];
            float gv = acc[ni][2][r];
            float ov = acc[ni][3][r];
            float si = 1.f / (1.f + __expf(-iv));
            float sf = 1.f / (1.f + __expf(-fv));
            float tg = 1.f - 2.f / (__expf(2.f * gv) + 1.f);
            float so = 1.f / (1.f + __expf(-ov));
            float c1 = c0v[ni][r] * sf + si * tg;
            float th = 1.f - 2.f / (__expf(2.f * c1) + 1.f);
            c1v[r] = c1;
            h1v[ni][r] = so + th;
        }
        int g4 = ni * 4 + lk;
        *reinterpret_cast<f32x4*>(&slot[lr * 32 + ((g4 ^ (lr & 7)) * 4)]) = c1v;
    }
    FLUSH(BH, b0, b1);

    // ---- plane 1: h_1 ----
    #pragma unroll
    for (int ni = 0; ni < 2; ++ni) {
        int g4 = ni * 4 + lk;
        *reinterpret_cast<f32x4*>(&slot[lr * 32 + ((g4 ^ (lr & 7)) * 4)]) = h1v[ni];
    }
    FLUSH(0, b2, b3);

    // ---- planes 2..5: raw gates I, F, G, O ----
    #pragma unroll
    for (int ni = 0; ni < 2; ++ni) {
        int g4 = ni * 4 + lk;
        *reinterpret_cast<f32x4*>(&slot[lr * 32 + ((g4 ^ (lr & 7)) * 4)]) = acc[ni][0];
    }
    FLUSH(2 * BH, b4, b5);

    #pragma unroll
    for (int ni = 0; ni < 2; ++ni) {
        int g4 = ni * 4 + lk;
        *reinterpret_cast<f32x4*>(&slot[lr * 32 + ((g4 ^ (lr & 7)) * 4)]) = acc[ni][1];
    }
    FLUSH(3 * BH, b6, b7);

    #pragma unroll
    for (int ni = 0; ni < 2; ++ni) {
        int g4 = ni * 4 + lk;
        *reinterpret_cast<f32x4*>(&slot[lr * 32 + ((g4 ^ (lr & 7)) * 4)]) = acc[ni][2];
    }
    FLUSH(4 * BH, b0, b1);   // redefine b0/b1 -> counted vmcnt, 8 deep

    #pragma unroll
    for (int ni = 0; ni < 2; ++ni) {
        int g4 = ni * 4 + lk;
        *reinterpret_cast<f32x4*>(&slot[lr * 32 + ((g4 ^ (lr & 7)) * 4)]) = acc[ni][3];
    }
    FLUSH(5 * BH, b2, b3);

    // keep late buffers live so the allocator gives all 8 distinct registers
    asm volatile("" :: "v"(b4), "v"(b5), "v"(b6), "v"(b7));
    #undef WSLOT
    #undef FLUSH
}

extern "C" void kernel_launch(void* const* d_in, const int* in_sizes, int n_in,
                              void* d_out, int out_size, void* d_ws, size_t ws_size,
                              hipStream_t stream) {
    const float* x  = (const float*)d_in[0];
    const float* h0 = (const float*)d_in[1];
    const float* c0 = (const float*)d_in[2];
    const float* ih = (const float*)d_in[3];
    const float* hh = (const float*)d_in[4];
    const float* ib = (const float*)d_in[5];
    const float* hb = (const float*)d_in[6];
    float* out = (float*)d_out;

    unsigned short* Wp = (unsigned short*)d_ws;            // 512*256 bf16 = 256 KB
    float* bias = (float*)((char*)d_ws + 512 * 256 * 2);   // 512 f32

    long BH = in_sizes[2];      // B * H
    long B  = BH / HSZ;

    prep_kernel<<<64, 256, 0, stream>>>(ih, hh, ib, hb, Wp, bias);
    lstm_kernel<<<(int)(B / BM), NT, 0, stream>>>(x, h0, c0, Wp, bias, out, BH);
}

// Round 9
// 213.853 us; speedup vs baseline: 1.6524x; 1.4715x over previous
//
#include <hip/hip_runtime.h>
#include <hip/hip_bf16.h>

typedef __attribute__((ext_vector_type(8))) short short8;
typedef __attribute__((ext_vector_type(4))) float f32x4;

#define HSZ 128
#define BM  32
#define NT  512

__device__ __forceinline__ unsigned short f2bf(float f) {
    union { float f; unsigned int u; } c; c.f = f;
    return (unsigned short)((c.u + 0x7FFFu + ((c.u >> 16) & 1u)) >> 16);
}

// Pack W (bf16) as Wp[col][k] (k contiguous, 16B-aligned fragments).
// W[k][g*128+i] = ih[g*128+k][i] (k<128) else hh[g*128+(k-128)][i].
__global__ void prep_kernel(const float* __restrict__ ih, const float* __restrict__ hh,
                            const float* __restrict__ ib, const float* __restrict__ hb,
                            unsigned short* __restrict__ Wp, float* __restrict__ bias) {
    int tid = blockIdx.x * blockDim.x + threadIdx.x;   // 0..16383
    int col = tid >> 5;                                // 0..511
    int kg  = tid & 31;                                // 0..31
    int g = col >> 7, i = col & 127;
    short8 pk;
    #pragma unroll
    for (int j = 0; j < 8; ++j) {
        int k = kg * 8 + j;
        float v = (k < HSZ) ? ih[(g * HSZ + k) * HSZ + i]
                            : hh[(g * HSZ + (k - HSZ)) * HSZ + i];
        pk[j] = (short)f2bf(v);
    }
    *reinterpret_cast<short8*>(Wp + col * 256 + kg * 8) = pk;
    if (kg == 0) bias[col] = ib[col] + hb[col];
}

__global__ __launch_bounds__(NT, 6)   // force <=85 regs -> 6 waves/SIMD = 24/CU
void lstm_kernel(const float* __restrict__ x, const float* __restrict__ h0,
                 const float* __restrict__ c0,
                 const unsigned short* __restrict__ Wp,
                 const float* __restrict__ biasp,
                 float* __restrict__ out, long BH) {
    constexpr int PITCH = 264;                  // shorts per A-LDS row
    __shared__ unsigned short A_lds[BM * PITCH];   // 16.9 KB
    __shared__ float S[8][640];                    // per-wave 32x16 f32 slot, pitch 20

    const int t = threadIdx.x;
    const long rowBase = (long)blockIdx.x * BM;

    // ---- stage A = [x | h0] (32 rows x 256 k) as bf16 into LDS ----
    {
        const float4* x4 = reinterpret_cast<const float4*>(x + rowBase * HSZ);
        const float4* h4 = reinterpret_cast<const float4*>(h0 + rowBase * HSZ);
        #pragma unroll
        for (int j = 0; j < 2; ++j) {
            int fi = t + j * NT;               // 0..1023
            int row = fi >> 5;
            int c4  = fi & 31;
            float4 vx = x4[fi];
            float4 vh = h4[fi];
            ushort4 px; px.x = f2bf(vx.x); px.y = f2bf(vx.y); px.z = f2bf(vx.z); px.w = f2bf(vx.w);
            ushort4 ph; ph.x = f2bf(vh.x); ph.y = f2bf(vh.y); ph.z = f2bf(vh.z); ph.w = f2bf(vh.w);
            *reinterpret_cast<ushort4*>(&A_lds[row * PITCH + c4 * 4]) = px;
            *reinterpret_cast<ushort4*>(&A_lds[row * PITCH + HSZ + c4 * 4]) = ph;
        }
    }
    __syncthreads();   // the ONLY block-wide barrier

    const int lane = t & 63;
    const int wid  = t >> 6;           // 0..7 = 16-col slice within each gate
    const int wn = wid;
    const int lr = lane & 15;
    const int lk = lane >> 4;          // k-group (8 bf16)

    const char* Ab = reinterpret_cast<const char*>(A_lds) + lr * (PITCH * 2) + lk * 16;
    const char* Wb = reinterpret_cast<const char*>(Wp) + (wn * 16 + lr) * 512 + lk * 16;

    f32x4 acc[2][4] = {};   // [mi][gate], 32 regs

    #pragma unroll
    for (int ks = 0; ks < 8; ++ks) {
        short8 a0 = *reinterpret_cast<const short8*>(Ab + ks * 64);
        short8 a1 = *reinterpret_cast<const short8*>(Ab + 16 * (PITCH * 2) + ks * 64);
        #pragma unroll
        for (int g = 0; g < 4; ++g) {
            short8 w = *reinterpret_cast<const short8*>(Wb + (g * 128) * 512 + ks * 64);
            // Swapped operands: D col = batch row (lr), lane's 4 regs = gate cols lk*4+r
            acc[0][g] = __builtin_amdgcn_mfma_f32_16x16x32_bf16(w, a0, acc[0][g], 0, 0, 0);
            acc[1][g] = __builtin_amdgcn_mfma_f32_16x16x32_bf16(w, a1, acc[1][g], 0, 0, 0);
        }
    }

    // ---- c0 fragment loads (before any stores; no vmcnt entanglement) ----
    f32x4 c0v[2];
    #pragma unroll
    for (int mi = 0; mi < 2; ++mi) {
        long pos = (rowBase + mi * 16 + lr) * HSZ + wn * 16 + lk * 4;
        c0v[mi] = *reinterpret_cast<const f32x4*>(c0 + pos);
    }

    // ---- fold bias into acc ----
    #pragma unroll
    for (int g = 0; g < 4; ++g) {
        f32x4 bg = *reinterpret_cast<const f32x4*>(biasp + g * HSZ + wn * 16 + lk * 4);
        acc[0][g] += bg;
        acc[1][g] += bg;
    }

    // ---- wave-local epilogue: private slot, pitch-20 (conflict-free), no barriers ----
    float* slot = S[wid];
    const int rr0 = lane >> 2;         // readback row 0..15 within mi-half
    const int gg0 = lane & 3;          // readback 16B granule within 64B segment
    const long cb = (long)(wn * 16 + gg0 * 4);

    // compute c1 & h1 (h1 held in regs while c1 round-trips)
    f32x4 c1v[2], h1v[2];
    #pragma unroll
    for (int mi = 0; mi < 2; ++mi) {
        #pragma unroll
        for (int r = 0; r < 4; ++r) {
            float iv = acc[mi][0][r];
            float fv = acc[mi][1][r];
            float gv = acc[mi][2][r];
            float ov = acc[mi][3][r];
            float si = 1.f / (1.f + __expf(-iv));
            float sf = 1.f / (1.f + __expf(-fv));
            float tg = 1.f - 2.f / (__expf(2.f * gv) + 1.f);
            float so = 1.f / (1.f + __expf(-ov));
            float c1 = c0v[mi][r] * sf + si * tg;
            float th = 1.f - 2.f / (__expf(2.f * c1) + 1.f);
            c1v[mi][r] = c1;
            h1v[mi][r] = so + th;
        }
    }

    // plane sequence: c1, h1, I, F, G, O through the single slot (LDS in-order per wave)
    #define PUT(V) do { \
        *reinterpret_cast<f32x4*>(&slot[(0 * 16 + lr) * 20 + lk * 4]) = (V)[0]; \
        *reinterpret_cast<f32x4*>(&slot[(16 + lr) * 20 + lk * 4])     = (V)[1]; \
    } while (0)
    #define FLS(OB) do { \
        f32x4 v0 = *reinterpret_cast<const f32x4*>(&slot[rr0 * 20 + gg0 * 4]); \
        f32x4 v1 = *reinterpret_cast<const f32x4*>(&slot[(16 + rr0) * 20 + gg0 * 4]); \
        __builtin_nontemporal_store(v0, reinterpret_cast<f32x4*>(out + (OB) + (rowBase + rr0) * HSZ + cb)); \
        __builtin_nontemporal_store(v1, reinterpret_cast<f32x4*>(out + (OB) + (rowBase + 16 + rr0) * HSZ + cb)); \
    } while (0)

    PUT(c1v);  FLS(BH);
    PUT(h1v);  FLS(0);
    { f32x4 p[2] = { acc[0][0], acc[1][0] }; PUT(p); FLS(2 * BH); }
    { f32x4 p[2] = { acc[0][1], acc[1][1] }; PUT(p); FLS(3 * BH); }
    { f32x4 p[2] = { acc[0][2], acc[1][2] }; PUT(p); FLS(4 * BH); }
    { f32x4 p[2] = { acc[0][3], acc[1][3] }; PUT(p); FLS(5 * BH); }
    #undef PUT
    #undef FLS
}

extern "C" void kernel_launch(void* const* d_in, const int* in_sizes, int n_in,
                              void* d_out, int out_size, void* d_ws, size_t ws_size,
                              hipStream_t stream) {
    const float* x  = (const float*)d_in[0];
    const float* h0 = (const float*)d_in[1];
    const float* c0 = (const float*)d_in[2];
    const float* ih = (const float*)d_in[3];
    const float* hh = (const float*)d_in[4];
    const float* ib = (const float*)d_in[5];
    const float* hb = (const float*)d_in[6];
    float* out = (float*)d_out;

    unsigned short* Wp = (unsigned short*)d_ws;            // 512*256 bf16 = 256 KB
    float* bias = (float*)((char*)d_ws + 512 * 256 * 2);   // 512 f32

    long BH = in_sizes[2];      // B * H
    long B  = BH / HSZ;

    prep_kernel<<<64, 256, 0, stream>>>(ih, hh, ib, hb, Wp, bias);
    lstm_kernel<<<(int)(B / BM), NT, 0, stream>>>(x, h0, c0, Wp, bias, out, BH);
}

// Round 10
// 197.568 us; speedup vs baseline: 1.7886x; 1.0824x over previous
//
#include <hip/hip_runtime.h>
#include <hip/hip_bf16.h>

typedef __attribute__((ext_vector_type(8))) short short8;
typedef __attribute__((ext_vector_type(4))) float f32x4;

#define HSZ 128
#define BM  32
#define NT  512

__device__ __forceinline__ unsigned short f2bf(float f) {
    union { float f; unsigned int u; } c; c.f = f;
    return (unsigned short)((c.u + 0x7FFFu + ((c.u >> 16) & 1u)) >> 16);
}

// Pack W (bf16) as Wp[col][k] (k contiguous, 16B-aligned fragments).
// W[k][g*128+i] = ih[g*128+k][i] (k<128) else hh[g*128+(k-128)][i].
__global__ void prep_kernel(const float* __restrict__ ih, const float* __restrict__ hh,
                            const float* __restrict__ ib, const float* __restrict__ hb,
                            unsigned short* __restrict__ Wp, float* __restrict__ bias) {
    int tid = blockIdx.x * blockDim.x + threadIdx.x;   // 0..16383
    int col = tid >> 5;                                // 0..511
    int kg  = tid & 31;                                // 0..31
    int g = col >> 7, i = col & 127;
    short8 pk;
    #pragma unroll
    for (int j = 0; j < 8; ++j) {
        int k = kg * 8 + j;
        float v = (k < HSZ) ? ih[(g * HSZ + k) * HSZ + i]
                            : hh[(g * HSZ + (k - HSZ)) * HSZ + i];
        pk[j] = (short)f2bf(v);
    }
    *reinterpret_cast<short8*>(Wp + col * 256 + kg * 8) = pk;
    if (kg == 0) bias[col] = ib[col] + hb[col];
}

union SMem {
    unsigned short A[BM * 264];   // 16.9 KB bf16 activations (dead after MFMA)
    f32x4 T[2][BM * 32];          // 2 x 16 KB f32 output tiles (double buffer)
};

__global__ __launch_bounds__(NT, 6)   // <=85 regs -> 6 waves/SIMD = 3 blocks/CU
void lstm_kernel(const float* __restrict__ x, const float* __restrict__ h0,
                 const float* __restrict__ c0,
                 const unsigned short* __restrict__ Wp,
                 const float* __restrict__ biasp,
                 float* __restrict__ out, long BH) {
    constexpr int PITCH = 264;
    __shared__ SMem sm;

    const int t = threadIdx.x;
    const long rowBase = (long)blockIdx.x * BM;

    // ---- stage A = [x | h0] (32 rows x 256 k) as bf16 into LDS ----
    {
        const float4* x4 = reinterpret_cast<const float4*>(x + rowBase * HSZ);
        const float4* h4 = reinterpret_cast<const float4*>(h0 + rowBase * HSZ);
        #pragma unroll
        for (int j = 0; j < 2; ++j) {
            int fi = t + j * NT;               // 0..1023
            int row = fi >> 5;
            int c4  = fi & 31;
            float4 vx = x4[fi];
            float4 vh = h4[fi];
            ushort4 px; px.x = f2bf(vx.x); px.y = f2bf(vx.y); px.z = f2bf(vx.z); px.w = f2bf(vx.w);
            ushort4 ph; ph.x = f2bf(vh.x); ph.y = f2bf(vh.y); ph.z = f2bf(vh.z); ph.w = f2bf(vh.w);
            *reinterpret_cast<ushort4*>(&sm.A[row * PITCH + c4 * 4]) = px;
            *reinterpret_cast<ushort4*>(&sm.A[row * PITCH + HSZ + c4 * 4]) = ph;
        }
    }
    __syncthreads();

    const int lane = t & 63;
    const int wid  = t >> 6;           // 0..7 = 16-col slice within each gate
    const int wn = wid;
    const int lr = lane & 15;
    const int lk = lane >> 4;          // k-group (8 bf16)

    const char* Ab = reinterpret_cast<const char*>(sm.A) + lr * (PITCH * 2) + lk * 16;
    const char* Wb = reinterpret_cast<const char*>(Wp) + (wn * 16 + lr) * 512 + lk * 16;

    f32x4 acc[2][4] = {};   // [mi][gate], 32 AGPR

    #pragma unroll
    for (int ks = 0; ks < 8; ++ks) {
        short8 a0 = *reinterpret_cast<const short8*>(Ab + ks * 64);
        short8 a1 = *reinterpret_cast<const short8*>(Ab + 16 * (PITCH * 2) + ks * 64);
        #pragma unroll
        for (int g = 0; g < 4; ++g) {
            short8 w = *reinterpret_cast<const short8*>(Wb + (g * 128) * 512 + ks * 64);
            // Swapped operands: D col = batch row (lr), lane's 4 regs = gate cols lk*4+r
            acc[0][g] = __builtin_amdgcn_mfma_f32_16x16x32_bf16(w, a0, acc[0][g], 0, 0, 0);
            acc[1][g] = __builtin_amdgcn_mfma_f32_16x16x32_bf16(w, a1, acc[1][g], 0, 0, 0);
        }
    }

    // ---- c0 fragment loads ----
    f32x4 c0v[2];
    #pragma unroll
    for (int mi = 0; mi < 2; ++mi) {
        long pos = (rowBase + mi * 16 + lr) * HSZ + wn * 16 + lk * 4;
        c0v[mi] = *reinterpret_cast<const f32x4*>(c0 + pos);
    }

    // ---- fold bias into acc ----
    #pragma unroll
    for (int g = 0; g < 4; ++g) {
        f32x4 bg = *reinterpret_cast<const f32x4*>(biasp + g * HSZ + wn * 16 + lk * 4);
        acc[0][g] += bg;
        acc[1][g] += bg;
    }

    __syncthreads();   // A tile dead; LDS becomes output double-buffer

    // granule col for PUT: 0..31 = wn*4 + lk; XOR-swizzled by row&7
    #define SIDX(MI) ((MI * 16 + lr) * 32 + ((wn * 4 + lk) ^ (lr & 7)))

    auto flush = [&](const f32x4* T, long obase) {
        #pragma unroll
        for (int p = 0; p < 2; ++p) {
            int f = t + p * NT;               // 0..1023 granules
            int row = f >> 5, c = f & 31;
            f32x4 v = T[row * 32 + (c ^ (row & 7))];
            __builtin_nontemporal_store(v,
                reinterpret_cast<f32x4*>(out + obase + (rowBase + row) * (long)HSZ + c * 4));
        }
    };

    // ---- P0: c_1 -> T0 ----
    #pragma unroll
    for (int mi = 0; mi < 2; ++mi) {
        f32x4 v;
        #pragma unroll
        for (int r = 0; r < 4; ++r) {
            float iv = acc[mi][0][r];
            float fv = acc[mi][1][r];
            float gv = acc[mi][2][r];
            float si = 1.f / (1.f + __expf(-iv));
            float sf = 1.f / (1.f + __expf(-fv));
            float tg = 1.f - 2.f / (__expf(2.f * gv) + 1.f);
            v[r] = c0v[mi][r] * sf + si * tg;
        }
        sm.T[0][SIDX(mi)] = v;
    }
    __syncthreads();

    // ---- P1: flush c_1 || h_1 -> T1 (c_1 read back from T0) ----
    flush(sm.T[0], BH);
    #pragma unroll
    for (int mi = 0; mi < 2; ++mi) {
        f32x4 c1 = sm.T[0][SIDX(mi)];
        f32x4 v;
        #pragma unroll
        for (int r = 0; r < 4; ++r) {
            float ov = acc[mi][3][r];
            float so = 1.f / (1.f + __expf(-ov));
            float th = 1.f - 2.f / (__expf(2.f * c1[r]) + 1.f);
            v[r] = so + th;
        }
        sm.T[1][SIDX(mi)] = v;
    }
    __syncthreads();

    // ---- P2: flush h_1 || I -> T0 ----
    flush(sm.T[1], 0);
    #pragma unroll
    for (int mi = 0; mi < 2; ++mi) sm.T[0][SIDX(mi)] = acc[mi][0];
    __syncthreads();

    // ---- P3: flush I || F -> T1 ----
    flush(sm.T[0], 2 * BH);
    #pragma unroll
    for (int mi = 0; mi < 2; ++mi) sm.T[1][SIDX(mi)] = acc[mi][1];
    __syncthreads();

    // ---- P4: flush F || G -> T0 ----
    flush(sm.T[1], 3 * BH);
    #pragma unroll
    for (int mi = 0; mi < 2; ++mi) sm.T[0][SIDX(mi)] = acc[mi][2];
    __syncthreads();

    // ---- P5: flush G || O -> T1 ----
    flush(sm.T[0], 4 * BH);
    #pragma unroll
    for (int mi = 0; mi < 2; ++mi) sm.T[1][SIDX(mi)] = acc[mi][3];
    __syncthreads();

    // ---- P6: flush O ----
    flush(sm.T[1], 5 * BH);
    #undef SIDX
}

extern "C" void kernel_launch(void* const* d_in, const int* in_sizes, int n_in,
                              void* d_out, int out_size, void* d_ws, size_t ws_size,
                              hipStream_t stream) {
    const float* x  = (const float*)d_in[0];
    const float* h0 = (const float*)d_in[1];
    const float* c0 = (const float*)d_in[2];
    const float* ih = (const float*)d_in[3];
    const float* hh = (const float*)d_in[4];
    const float* ib = (const float*)d_in[5];
    const float* hb = (const float*)d_in[6];
    float* out = (float*)d_out;

    unsigned short* Wp = (unsigned short*)d_ws;            // 512*256 bf16 = 256 KB
    float* bias = (float*)((char*)d_ws + 512 * 256 * 2);   // 512 f32

    long BH = in_sizes[2];      // B * H
    long B  = BH / HSZ;

    prep_kernel<<<64, 256, 0, stream>>>(ih, hh, ib, hb, Wp, bias);
    lstm_kernel<<<(int)(B / BM), NT, 0, stream>>>(x, h0, c0, Wp, bias, out, BH);
}

// Round 11
// 189.752 us; speedup vs baseline: 1.8623x; 1.0412x over previous
//
#include <hip/hip_runtime.h>
#include <hip/hip_bf16.h>

typedef __attribute__((ext_vector_type(8))) short short8;
typedef __attribute__((ext_vector_type(4))) float f32x4;

#define HSZ 128
#define BM  32
#define NT  512

// lgkm-only barrier: orders LDS across waves WITHOUT draining vmcnt
// (global stores stay in flight across phases — the whole point).
#define LGKM_BARRIER() asm volatile("s_waitcnt lgkmcnt(0)\n\ts_barrier" ::: "memory")

__device__ __forceinline__ unsigned short f2bf(float f) {
    union { float f; unsigned int u; } c; c.f = f;
    return (unsigned short)((c.u + 0x7FFFu + ((c.u >> 16) & 1u)) >> 16);
}

// Pack W (bf16) as Wp[col][k] (k contiguous, 16B-aligned fragments).
// W[k][g*128+i] = ih[g*128+k][i] (k<128) else hh[g*128+(k-128)][i].
__global__ void prep_kernel(const float* __restrict__ ih, const float* __restrict__ hh,
                            const float* __restrict__ ib, const float* __restrict__ hb,
                            unsigned short* __restrict__ Wp, float* __restrict__ bias) {
    int tid = blockIdx.x * blockDim.x + threadIdx.x;   // 0..16383
    int col = tid >> 5;                                // 0..511
    int kg  = tid & 31;                                // 0..31
    int g = col >> 7, i = col & 127;
    short8 pk;
    #pragma unroll
    for (int j = 0; j < 8; ++j) {
        int k = kg * 8 + j;
        float v = (k < HSZ) ? ih[(g * HSZ + k) * HSZ + i]
                            : hh[(g * HSZ + (k - HSZ)) * HSZ + i];
        pk[j] = (short)f2bf(v);
    }
    *reinterpret_cast<short8*>(Wp + col * 256 + kg * 8) = pk;
    if (kg == 0) bias[col] = ib[col] + hb[col];
}

union SMem {
    unsigned short A[BM * 264];   // 16.9 KB bf16 activations (dead after MFMA)
    f32x4 T[2][BM * 32];          // 2 x 16 KB f32 output tiles (double buffer)
};

__global__ __launch_bounds__(NT, 6)   // <=85 regs -> 6 waves/SIMD = 3 blocks/CU
void lstm_kernel(const float* __restrict__ x, const float* __restrict__ h0,
                 const float* __restrict__ c0,
                 const unsigned short* __restrict__ Wp,
                 const float* __restrict__ biasp,
                 float* __restrict__ out, long BH) {
    constexpr int PITCH = 264;
    __shared__ SMem sm;

    const int t = threadIdx.x;
    const long rowBase = (long)blockIdx.x * BM;

    // ---- stage A = [x | h0] (32 rows x 256 k) as bf16 into LDS ----
    {
        const float4* x4 = reinterpret_cast<const float4*>(x + rowBase * HSZ);
        const float4* h4 = reinterpret_cast<const float4*>(h0 + rowBase * HSZ);
        #pragma unroll
        for (int j = 0; j < 2; ++j) {
            int fi = t + j * NT;               // 0..1023
            int row = fi >> 5;
            int c4  = fi & 31;
            float4 vx = x4[fi];
            float4 vh = h4[fi];
            ushort4 px; px.x = f2bf(vx.x); px.y = f2bf(vx.y); px.z = f2bf(vx.z); px.w = f2bf(vx.w);
            ushort4 ph; ph.x = f2bf(vh.x); ph.y = f2bf(vh.y); ph.z = f2bf(vh.z); ph.w = f2bf(vh.w);
            *reinterpret_cast<ushort4*>(&sm.A[row * PITCH + c4 * 4]) = px;
            *reinterpret_cast<ushort4*>(&sm.A[row * PITCH + HSZ + c4 * 4]) = ph;
        }
    }
    LGKM_BARRIER();

    const int lane = t & 63;
    const int wid  = t >> 6;           // 0..7 = 16-col slice within each gate
    const int wn = wid;
    const int lr = lane & 15;
    const int lk = lane >> 4;          // k-group (8 bf16)

    const char* Ab = reinterpret_cast<const char*>(sm.A) + lr * (PITCH * 2) + lk * 16;
    const char* Wb = reinterpret_cast<const char*>(Wp) + (wn * 16 + lr) * 512 + lk * 16;

    f32x4 acc[2][4] = {};   // [mi][gate], 32 AGPR

    #pragma unroll
    for (int ks = 0; ks < 8; ++ks) {
        short8 a0 = *reinterpret_cast<const short8*>(Ab + ks * 64);
        short8 a1 = *reinterpret_cast<const short8*>(Ab + 16 * (PITCH * 2) + ks * 64);
        #pragma unroll
        for (int g = 0; g < 4; ++g) {
            short8 w = *reinterpret_cast<const short8*>(Wb + (g * 128) * 512 + ks * 64);
            // Swapped operands: D col = batch row (lr), lane's 4 regs = gate cols lk*4+r
            acc[0][g] = __builtin_amdgcn_mfma_f32_16x16x32_bf16(w, a0, acc[0][g], 0, 0, 0);
            acc[1][g] = __builtin_amdgcn_mfma_f32_16x16x32_bf16(w, a1, acc[1][g], 0, 0, 0);
        }
    }

    // ---- c0 fragment loads (consumed at P4; long slack) ----
    f32x4 c0v[2];
    #pragma unroll
    for (int mi = 0; mi < 2; ++mi) {
        long pos = (rowBase + mi * 16 + lr) * HSZ + wn * 16 + lk * 4;
        c0v[mi] = *reinterpret_cast<const f32x4*>(c0 + pos);
    }

    // ---- fold bias into acc ----
    #pragma unroll
    for (int g = 0; g < 4; ++g) {
        f32x4 bg = *reinterpret_cast<const f32x4*>(biasp + g * HSZ + wn * 16 + lk * 4);
        acc[0][g] += bg;
        acc[1][g] += bg;
    }

    LGKM_BARRIER();   // A tile dead; LDS becomes output double-buffer

    // granule col for PUT: 0..31 = wn*4 + lk; XOR-swizzled by row&7
    #define SIDX(MI) ((MI * 16 + lr) * 32 + ((wn * 4 + lk) ^ (lr & 7)))

    auto flush = [&](const f32x4* T, long obase) {
        #pragma unroll
        for (int p = 0; p < 2; ++p) {
            int f = t + p * NT;               // 0..1023 granules
            int row = f >> 5, c = f & 31;
            f32x4 v = T[row * 32 + (c ^ (row & 7))];
            __builtin_nontemporal_store(v,
                reinterpret_cast<f32x4*>(out + obase + (rowBase + row) * (long)HSZ + c * 4));
        }
    };

    // ---- P0: I -> T0 ----
    #pragma unroll
    for (int mi = 0; mi < 2; ++mi) sm.T[0][SIDX(mi)] = acc[mi][0];
    LGKM_BARRIER();

    // ---- P1: flush I || F -> T1 ----
    flush(sm.T[0], 2 * BH);
    #pragma unroll
    for (int mi = 0; mi < 2; ++mi) sm.T[1][SIDX(mi)] = acc[mi][1];
    LGKM_BARRIER();

    // ---- P2: flush F || G -> T0 ----
    flush(sm.T[1], 3 * BH);
    #pragma unroll
    for (int mi = 0; mi < 2; ++mi) sm.T[0][SIDX(mi)] = acc[mi][2];
    LGKM_BARRIER();

    // ---- P3: flush G || O -> T1 ----
    flush(sm.T[0], 4 * BH);
    #pragma unroll
    for (int mi = 0; mi < 2; ++mi) sm.T[1][SIDX(mi)] = acc[mi][3];
    LGKM_BARRIER();

    // ---- P4: flush O || c_1 -> T0 (exp-heavy compute in store shadow) ----
    flush(sm.T[1], 5 * BH);
    #pragma unroll
    for (int mi = 0; mi < 2; ++mi) {
        f32x4 v;
        #pragma unroll
        for (int r = 0; r < 4; ++r) {
            float iv = acc[mi][0][r];
            float fv = acc[mi][1][r];
            float gv = acc[mi][2][r];
            float si = 1.f / (1.f + __expf(-iv));
            float sf = 1.f / (1.f + __expf(-fv));
            float tg = 1.f - 2.f / (__expf(2.f * gv) + 1.f);
            v[r] = c0v[mi][r] * sf + si * tg;
        }
        sm.T[0][SIDX(mi)] = v;
    }
    LGKM_BARRIER();

    // ---- P5: flush c_1 || h_1 -> T1 (c_1 read back from own T0 slot) ----
    flush(sm.T[0], BH);
    #pragma unroll
    for (int mi = 0; mi < 2; ++mi) {
        f32x4 c1 = sm.T[0][SIDX(mi)];
        f32x4 v;
        #pragma unroll
        for (int r = 0; r < 4; ++r) {
            float ov = acc[mi][3][r];
            float so = 1.f / (1.f + __expf(-ov));
            float th = 1.f - 2.f / (__expf(2.f * c1[r]) + 1.f);
            v[r] = so + th;
        }
        sm.T[1][SIDX(mi)] = v;
    }
    LGKM_BARRIER();

    // ---- P6: flush h_1 (no trailing drain needed before endpgm) ----
    flush(sm.T[1], 0);
    #undef SIDX
}

extern "C" void kernel_launch(void* const* d_in, const int* in_sizes, int n_in,
                              void* d_out, int out_size, void* d_ws, size_t ws_size,
                              hipStream_t stream) {
    const float* x  = (const float*)d_in[0];
    const float* h0 = (const float*)d_in[1];
    const float* c0 = (const float*)d_in[2];
    const float* ih = (const float*)d_in[3];
    const float* hh = (const float*)d_in[4];
    const float* ib = (const float*)d_in[5];
    const float* hb = (const float*)d_in[6];
    float* out = (float*)d_out;

    unsigned short* Wp = (unsigned short*)d_ws;            // 512*256 bf16 = 256 KB
    float* bias = (float*)((char*)d_ws + 512 * 256 * 2);   // 512 f32

    long BH = in_sizes[2];      // B * H
    long B  = BH / HSZ;

    prep_kernel<<<64, 256, 0, stream>>>(ih, hh, ib, hb, Wp, bias);
    lstm_kernel<<<(int)(B / BM), NT, 0, stream>>>(x, h0, c0, Wp, bias, out, BH);
}